// Round 9
// baseline (168.269 us; speedup 1.0000x reference)
//
#include <hip/hip_runtime.h>
#include <hip/hip_fp16.h>

typedef _Float16 h2 __attribute__((ext_vector_type(2)));

#define BB 4
#define CIN 64
#define COUT 64
#define NN 40960
#define KK 16
#define NB 128                 // n-tile per gemm block
#define GB2 (BB * NN / NB)     // 1280 gemm blocks
#define HP 32                  // idx shares per batch
#define HWORDS (NN / 4)        // 10240 u32 words (4 u8 bins per word)
#define TP 37                  // k_final tile pitch

__device__ __forceinline__ void gl2lds16(const float* g, float* l) {
    __builtin_amdgcn_global_load_lds(
        (const __attribute__((address_space(1))) void*)g,
        (__attribute__((address_space(3))) void*)l, 16, 0, 0);
}

// Privatized histogram, u8-packed: block (b,p) bins its idx share into 40KB
// LDS, plain stores. No global atomics. max bin ~8 << 255.
__global__ __launch_bounds__(256) void k_hist(const int* __restrict__ idx,
                                              unsigned int* __restrict__ hist) {
    __shared__ unsigned int bins[HWORDS];   // 40 KB
    const int tid = threadIdx.x;
    const int b = blockIdx.x >> 5;          // HP = 32
    const int p = blockIdx.x & (HP - 1);

#pragma unroll
    for (int i = 0; i < HWORDS / 256; ++i) bins[i * 256 + tid] = 0u;
    __syncthreads();

    const int SHARE = NN * KK / HP;         // 20480
    const int4* src = (const int4*)(idx + (size_t)b * NN * KK + (size_t)p * SHARE);
#pragma unroll 4
    for (int i = 0; i < SHARE / 4 / 256; ++i) {
        int4 v = src[i * 256 + tid];
        atomicAdd(&bins[(unsigned)v.x >> 2], 1u << (((unsigned)v.x & 3) * 8));
        atomicAdd(&bins[(unsigned)v.y >> 2], 1u << (((unsigned)v.y & 3) * 8));
        atomicAdd(&bins[(unsigned)v.z >> 2], 1u << (((unsigned)v.z & 3) * 8));
        atomicAdd(&bins[(unsigned)v.w >> 2], 1u << (((unsigned)v.w & 3) * 8));
    }
    __syncthreads();
    unsigned int* dst = hist + (size_t)blockIdx.x * HWORDS;
#pragma unroll
    for (int i = 0; i < HWORDS / 256; ++i) dst[i * 256 + tid] = bins[i * 256 + tid];
}

// g[b][n][o] (fp16, split lo/hi) = sum_c W[o][c]*feat[b][c][n]; fused stats.
// m97-style: feat staged via global_load_lds(16B); tile 64o x 128n, 1280 blks.
__global__ __launch_bounds__(256) void k_gemm(const float* __restrict__ feat,
                                              const float* __restrict__ W,
                                              const unsigned char* __restrict__ hist,
                                              __half* __restrict__ g_lo,
                                              __half* __restrict__ g_hi,
                                              float* __restrict__ partials) {
    __shared__ __align__(16) float wsm[64 * 68];   // Wt_s[c][o]; reused as red[2][64][33]
    __shared__ __align__(16) float fbuf[16 * 128]; // 8 KB DMA staging
    __shared__ float w_s[128];

    const int tid  = threadIdx.x;
    const int lane = tid & 63;
    const int wave = tid >> 6;
    const int b    = blockIdx.x / (NN / NB);
    const int n0   = (blockIdx.x % (NN / NB)) * NB;

    // merge u8 private histograms for this block's 128 bins (coalesced bytes)
    if (tid < 128) {
        const int n = n0 + tid;
        unsigned s = 1u;                     // +1 self reference
#pragma unroll
        for (int p = 0; p < HP; ++p)
            s += hist[(size_t)(b * HP + p) * NN + n];
        w_s[tid] = (float)s;
    }

    // stage W transposed (coalesced read, once)
#pragma unroll
    for (int it = 0; it < 16; ++it) {
        int c = tid & 63;
        int o = it * 4 + (tid >> 6);
        wsm[c * 68 + o] = W[o * 64 + c];
    }

    const int to = tid & 7;    // o-octet
    const int tn = tid >> 3;   // n-quad (0..31)

    float acc[8][4];
#pragma unroll
    for (int i = 0; i < 8; ++i)
#pragma unroll
        for (int j = 0; j < 4; ++j) acc[i][j] = 0.f;

    const float* fb = feat + (size_t)b * CIN * NN + n0;

    for (int cb = 0; cb < 4; ++cb) {
        __syncthreads();   // previous compute done before overwrite
        // DMA 16 c-rows x 128 n: wave stages row-pairs (2 calls/wave)
#pragma unroll
        for (int l2 = 0; l2 < 2; ++l2) {
            int row = (wave * 2 + l2) * 2;                 // 0,2,..,14
            const float* gp = fb + (size_t)(cb * 16 + row + (lane >> 5)) * NN
                                 + (size_t)(lane & 31) * 4;
            gl2lds16(gp, &fbuf[row * 128]);
        }
        __syncthreads();   // drain DMA

#pragma unroll
        for (int cc = 0; cc < 16; ++cc) {
            const float* wr = &wsm[(cb * 16 + cc) * 68 + to * 8];
            float4 w0 = *(const float4*)&wr[0];
            float4 w1 = *(const float4*)&wr[4];
            float4 f0 = *(const float4*)&fbuf[cc * 128 + tn * 4];
            float wv[8] = {w0.x, w0.y, w0.z, w0.w, w1.x, w1.y, w1.z, w1.w};
            float fv[4] = {f0.x, f0.y, f0.z, f0.w};
#pragma unroll
            for (int i = 0; i < 8; ++i)
#pragma unroll
                for (int j = 0; j < 4; ++j)
                    acc[i][j] = fmaf(wv[i], fv[j], acc[i][j]);
        }
    }

    // store g fp16, split halves: 4 n-rows per thread
    __half* glo_b = g_lo + ((size_t)b * NN + n0) * 32;
    __half* ghi_b = g_hi + ((size_t)b * NN + n0) * 32;
#pragma unroll
    for (int j = 0; j < 4; ++j) {
        int n = tn * 4 + j;
        union { uint4 u; h2 h[4]; } P;
#pragma unroll
        for (int h = 0; h < 4; ++h) {
            h2 t;
            t.x = (_Float16)acc[2 * h][j];
            t.y = (_Float16)acc[2 * h + 1][j];
            P.h[h] = t;
        }
        __half* dst = (to < 4) ? (glo_b + (size_t)n * 32 + to * 8)
                               : (ghi_b + (size_t)n * 32 + (to - 4) * 8);
        *(uint4*)dst = P.u;
    }

    // fused weighted stats (fp32 accumulators, pre-rounding)
    float wgt[4];
#pragma unroll
    for (int j = 0; j < 4; ++j) wgt[j] = w_s[tn * 4 + j];
    float s1[8], s2[8];
#pragma unroll
    for (int i = 0; i < 8; ++i) { s1[i] = 0.f; s2[i] = 0.f; }
#pragma unroll
    for (int j = 0; j < 4; ++j)
#pragma unroll
        for (int i = 0; i < 8; ++i) {
            float wv = wgt[j] * acc[i][j];
            s1[i] += wv;
            s2[i] += wv * acc[i][j];
        }

    __syncthreads();           // done reading wsm as W
    float* red = wsm;          // [2][64][33], 4224 <= 4352 floats
#pragma unroll
    for (int i = 0; i < 8; ++i) {
        int o = to * 8 + i;
        red[o * 33 + tn]        = s1[i];
        red[2112 + o * 33 + tn] = s2[i];
    }
    __syncthreads();
    if (tid < 128) {
        int arr = tid >> 6, o = tid & 63;
        const float* base = red + arr * 2112 + o * 33;
        float s = 0.f;
#pragma unroll
        for (int t = 0; t < 32; ++t) s += base[t];
        partials[blockIdx.x * 128 + arr * 64 + o] = s;
    }
}

__global__ __launch_bounds__(1024) void k_finalize(const float* __restrict__ partials,
                                                   const float* __restrict__ gamma,
                                                   const float* __restrict__ beta,
                                                   _Float16* __restrict__ params_h) {
    const int i = threadIdx.x & 127;
    const int r = threadIdx.x >> 7;
    double a0 = 0, a1 = 0, a2 = 0, a3 = 0;
    for (int base = r; base < GB2; base += 32) {
        a0 += (double)partials[(base)      * 128 + i];
        a1 += (double)partials[(base + 8)  * 128 + i];
        a2 += (double)partials[(base + 16) * 128 + i];
        a3 += (double)partials[(base + 24) * 128 + i];
    }
    __shared__ double red[8][128];
    red[r][i] = (a0 + a1) + (a2 + a3);
    __syncthreads();
    if (threadIdx.x < 64) {
        const int o = threadIdx.x;
        double s1 = 0.0, s2 = 0.0;
#pragma unroll
        for (int rr = 0; rr < 8; ++rr) { s1 += red[rr][o]; s2 += red[rr][64 + o]; }
        const double TOT = (double)BB * NN * (KK + 1);
        double mean = s1 / TOT;
        double var  = s2 / TOT - mean * mean;
        double inv  = 1.0 / sqrt(var + 1e-6);
        float scale = (float)inv * gamma[o];
        float shift = beta[o] - (float)mean * scale;
        params_h[o]      = (_Float16)scale;
        params_h[64 + o] = (_Float16)shift;
    }
}

// out[b][o][n] = sum over {n, idx[b,n,:]} of leakyrelu(g*scale+shift)
// GRID = 8 * (NN/256) = 1280; p = (b, half) -> XCD partition.
__global__ __launch_bounds__(256) void k_final(const __half* __restrict__ g_lo,
                                               const __half* __restrict__ g_hi,
                                               const int* __restrict__ idx,
                                               const _Float16* __restrict__ params_h,
                                               float* __restrict__ out) {
    const int tid  = threadIdx.x;
    const int lane = tid & 63;
    const int wave = tid >> 6;
    const int p     = blockIdx.x & 7;
    const int chunk = blockIdx.x >> 3;      // 0..159
    const int b     = p >> 1;
    const int h     = p & 1;
    const int n0    = chunk * 256;

    __shared__ int   idx_s[256 * 17];
    __shared__ float tile[256 * TP];

    {
        const int4* src = (const int4*)(idx + ((size_t)b * NN + n0) * KK);
#pragma unroll
        for (int i = 0; i < 4; ++i) {
            int e = i * 256 + tid;
            int4 v = src[e];
            int pt = e >> 2, k4 = (e & 3) * 4;
            idx_s[pt * 17 + k4 + 0] = v.x;
            idx_s[pt * 17 + k4 + 1] = v.y;
            idx_s[pt * 17 + k4 + 2] = v.z;
            idx_s[pt * 17 + k4 + 3] = v.w;
        }
    }

    const int q = (lane & 3) * 8;
    h2 sc2[4], sh2[4];
#pragma unroll
    for (int hh = 0; hh < 4; ++hh) {
        h2 a, s;
        a.x = params_h[h * 32 + q + 2 * hh];      a.y = params_h[h * 32 + q + 2 * hh + 1];
        s.x = params_h[64 + h * 32 + q + 2 * hh]; s.y = params_h[64 + h * 32 + q + 2 * hh + 1];
        sc2[hh] = a; sh2[hh] = s;
    }
    __syncthreads();

    const __half* gb = (h ? g_hi : g_lo) + (size_t)b * NN * 32;

#pragma unroll
    for (int it = 0; it < 4; ++it) {
        const int pt = wave * 64 + it * 16 + (lane >> 2);
        h2 acc[4];
#pragma unroll
        for (int hh = 0; hh < 4; ++hh) acc[hh] = (h2)(_Float16)0;

#pragma unroll
        for (int k = -1; k < KK; ++k) {
            int m = (k < 0) ? (n0 + pt) : idx_s[pt * 17 + k];
            union { uint4 u; h2 h[4]; } U;
            U.u = *(const uint4*)(gb + (size_t)m * 32 + q);
#pragma unroll
            for (int hh = 0; hh < 4; ++hh) {
                h2 t = U.h[hh] * sc2[hh] + sh2[hh];
                acc[hh] += __builtin_elementwise_max(t, t * (_Float16)0.2f);
            }
        }
        float* tr = &tile[pt * TP + q];
#pragma unroll
        for (int hh = 0; hh < 4; ++hh) {
            tr[2 * hh]     = (float)acc[hh].x;
            tr[2 * hh + 1] = (float)acc[hh].y;
        }
    }
    __syncthreads();

    const int oo   = tid >> 3;
    const int nsub = tid & 7;
    float* ob = out + ((size_t)(b * 64 + h * 32 + oo)) * NN + n0;
#pragma unroll
    for (int pass = 0; pass < 8; ++pass) {
        int nl = pass * 32 + nsub * 4;
        float4 v = make_float4(tile[(nl + 0) * TP + oo], tile[(nl + 1) * TP + oo],
                               tile[(nl + 2) * TP + oo], tile[(nl + 3) * TP + oo]);
        *(float4*)&ob[nl] = v;
    }
}

extern "C" void kernel_launch(void* const* d_in, const int* in_sizes, int n_in,
                              void* d_out, int out_size, void* d_ws, size_t ws_size,
                              hipStream_t stream) {
    const float* feat  = (const float*)d_in[0];
    const float* W     = (const float*)d_in[1];
    const float* gamma = (const float*)d_in[2];
    const float* beta  = (const float*)d_in[3];
    const int*   idx   = (const int*)d_in[4];
    float* out = (float*)d_out;

    char* ws = (char*)d_ws;
    __half* g_lo = (__half*)ws;
    size_t off = (size_t)BB * NN * 32 * sizeof(__half);               // 10,485,760
    __half* g_hi = (__half*)(ws + off);
    off += (size_t)BB * NN * 32 * sizeof(__half);                     // +10,485,760
    unsigned char* hist = (unsigned char*)(ws + off);
    off += (size_t)BB * HP * NN;                                      // +5,242,880
    float* partials = (float*)(ws + off);
    off += (size_t)GB2 * 128 * sizeof(float);                         // +655,360
    _Float16* params_h = (_Float16*)(ws + off);

    k_hist<<<BB * HP, 256, 0, stream>>>(idx, (unsigned int*)hist);
    k_gemm<<<GB2, 256, 0, stream>>>(feat, W, hist, g_lo, g_hi, partials);
    k_finalize<<<1, 1024, 0, stream>>>(partials, gamma, beta, params_h);
    k_final<<<8 * (NN / 256), 256, 0, stream>>>(g_lo, g_hi, idx, params_h, out);
}